// Round 5
// baseline (254.924 us; speedup 1.0000x reference)
//
#include <hip/hip_runtime.h>
#include <math.h>

// WaveLM: logits[b,t,v] = sum_{t'<t} g(id[b,t'], v)
// g(u,v) = 2 * sum_{i,j in 1..H} (A_u/i^dec)(A_v/j^dec) * sinc(2*(f_u*i - f_v*j))
// sinc(2d) = sin(2*pi*d)/(2*pi*d), sinc(0)=1
//
// R10: - 1 v per lane (was 2 packed). R9 showed VGPR=84 comes from the
//        per-lane v-side working set (2x arrays for the v-pair), not from
//        u-side pipelining. Wave64 f32 issue cost per ELEMENT is identical
//        packed vs plain (pk = 4cyc/128 elem, plain = 2cyc/64 elem), so
//        halving the arrays costs no ALU time, fits ~56 VGPR (<=64 -> 8
//        waves/SIMD, 2x occupancy) and doubles wave-level parallelism.
//        Inline-asm pk wrappers removed; per-element arithmetic unchanged
//        (rcp now direct per-component instead of the pair trick).
//      - u-side compression kept from R9 (4 s_loads/token: f, A, s1, c1;
//        sin/cos by tab's exact recurrence; rp from decay once per block).
//      - GT=16 fused segment scan + id-only prefetch kept; fused-lookback
//        addbase kept; guarded rare path now per-lane.

typedef float v4f __attribute__((ext_vector_type(4)));

constexpr int cB = 4, cT = 512, cV = 8000, cH = 7;
constexpr int GT = 16;                // tokens per wavelm_g block == seglen
constexpr int NSEG = cT / GT;         // 32 segments
constexpr int NPLANE = 28;            // table planes

__global__ __launch_bounds__(256) void wavelm_tab(
    const float* __restrict__ freq, const float* __restrict__ amp,
    const float* __restrict__ decay_p, float* __restrict__ tab)
{
    const int v = blockIdx.x * 256 + threadIdx.x;
    if (v >= cV) return;
    const float decay = decay_p[0];
    const float f = freq[v], A = amp[v];
    const float p2 = __builtin_amdgcn_exp2f(-decay);
    const float p3 = __builtin_amdgcn_exp2f(-decay * 1.5849625007f);
    const float p5 = __builtin_amdgcn_exp2f(-decay * 2.3219280949f);
    const float p7 = __builtin_amdgcn_exp2f(-decay * 2.8073549221f);
    const float rp[7] = {1.f, p2, p3, p2*p2, p5, p2*p3, p7};
    const float xr = f - rintf(f);
    const float s1 = __builtin_amdgcn_sinf(xr);
    const float c1 = __builtin_amdgcn_cosf(xr);
    float s = s1, c = c1;
#pragma unroll
    for (int k = 0; k < cH; ++k) {
        if (k) { const float sp = s, cp = c;
                 s = fmaf(sp, c1,  cp * s1);
                 c = fmaf(cp, c1, -(sp * s1)); }
        tab[(size_t)k * cV + v]        = s;
        tab[(size_t)(7 + k) * cV + v]  = c;
        tab[(size_t)(14 + k) * cV + v] = A * rp[k];
        tab[(size_t)(21 + k) * cV + v] = f * (float)(k + 1);
    }
}

__global__ __launch_bounds__(256) void wavelm_g(
    const int* __restrict__ ids, const float* __restrict__ tab,
    const float* __restrict__ decay_p,
    float* __restrict__ out, float* __restrict__ segsum, const int segmode)
{
    const int bs  = blockIdx.y;                     // (b, seg) flattened
    const int bt0 = bs * GT;
    const int v   = blockIdx.x * 256 + threadIdx.x; // one vocab element/lane
    // wave-uniform early exit for fully-invalid waves (v base >= cV)
    if (v - (threadIdx.x & 63) >= cV) return;
    const bool valid = (v < cV);
    const int vc = valid ? v : 0;

    // ---- v-side setup once, amortized over GT tokens ----
    float nb[cH], sBw[cH], cBw[cH];
#pragma unroll
    for (int j = 0; j < cH; ++j) {
        const float s = tab[(size_t)j * cV + vc];
        const float c = tab[(size_t)(7 + j) * cV + vc];
        const float w = tab[(size_t)(14 + j) * cV + vc];
        const float a = tab[(size_t)(21 + j) * cV + vc];
        const float ws = w * 0.15915494309189535f;  // w/(2pi)
        sBw[j] = s * ws;
        cBw[j] = c * ws;
        nb[j] = -a;                                 // negated: d = au + nb
    }

    // rp[k] = (k+1)^-decay, uniform across lanes; identical ops to wavelm_tab
    const float decay = decay_p[0];
    const float q2 = __builtin_amdgcn_exp2f(-decay);
    const float q3 = __builtin_amdgcn_exp2f(-decay * 1.5849625007f);
    const float q5 = __builtin_amdgcn_exp2f(-decay * 2.3219280949f);
    const float q7 = __builtin_amdgcn_exp2f(-decay * 2.8073549221f);
    const float rp[7] = {1.f, q2, q3, q2*q2, q5, q2*q3, q7};

    float acc = 0.f;                                // running segment prefix

    int idc = ids[bt0];                             // current token id (SGPR)
    for (int g = 0; g < GT; ++g) {
        // prefetch only the NEXT id (1 SGPR); breaks the id->tab serial chain
        const int idn = (g + 1 < GT) ? ids[bt0 + g + 1] : idc;

        // u-side: 4 wave-uniform scalar loads; rest derived in-register
        const float fu  = tab[(size_t)21 * cV + idc];   // f*1 == f
        const float Au  = tab[(size_t)14 * cV + idc];   // A*rp[0] == A
        const float s1u = tab[idc];                     // sin(2pi f)
        const float c1u = tab[(size_t)7 * cV + idc];    // cos(2pi f)

        float accx = 0.f;
        float mn = 3.0e38f, mx = 0.0f;
        float su = s1u, cu = c1u;                   // sin/cos(2pi f (i+1))
#pragma unroll
        for (int i = 0; i < cH; ++i) {
            if (i) { const float sp = su, cp = cu;
                     su = fmaf(sp, c1u,  cp * s1u);
                     cu = fmaf(cp, c1u, -(sp * s1u)); }
            const float au = fu * (float)(i + 1);   // same op as tab plane 21
            float d[cH], p[cH];
#pragma unroll
            for (int j = 0; j < cH; ++j) d[j] = au + nb[j];
            p[0] = d[0];
#pragma unroll
            for (int j = 1; j < cH; ++j) p[j] = p[j-1] * d[j];
            mn = fminf(mn, fabsf(p[6]));
            mx = fmaxf(mx, fabsf(p[6]));
            float r = __builtin_amdgcn_rcpf(p[6]);  // 1/(d0..d6)
            float accS = 0.f, accC = 0.f;
#pragma unroll
            for (int j = cH - 1; j >= 1; --j) {
                const float inv = r * p[j-1];       // 1/d[j]
                accS = fmaf(cBw[j], inv, accS);
                accC = fmaf(sBw[j], inv, accC);
                r = r * d[j];
            }
            accS = fmaf(cBw[0], r, accS);
            accC = fmaf(sBw[0], r, accC);
            // sum_j sn_j*inv_j = su*accS - cu*accC
            const float tx = fmaf(su, accS, -(cu * accC));
            accx = fmaf(rp[i], tx, accx);
        }

        // rare guarded path: exact-zero d (v==id), underflow, overflow
        if (mn < 1e-37f || mx > 1e37f) {
            accx = 0.f;
            float s2 = s1u, c2 = c1u;
#pragma unroll
            for (int i = 0; i < cH; ++i) {
                if (i) { const float sp = s2, cp = c2;
                         s2 = fmaf(sp, c1u,  cp * s1u);
                         c2 = fmaf(cp, c1u, -(sp * s1u)); }
                const float au = fu * (float)(i + 1);
                float ax = 0.f;
#pragma unroll
                for (int j = 0; j < cH; ++j) {
                    const float w = tab[(size_t)(14 + j) * cV + vc];
                    const float dx = au + nb[j];
                    const float snx = fmaf(s2, cBw[j], -(c2 * sBw[j]));
                    float qx = snx * __builtin_amdgcn_rcpf(dx);
                    qx = (dx == 0.f) ? w : qx;
                    ax += qx;
                }
                accx = fmaf(rp[i], ax, accx);
            }
        }

        if (valid) {
            const float res = (2.f * Au) * accx;
            const size_t o = (size_t)(bt0 + g) * cV + (size_t)vc;
            out[o] = segmode ? acc : res;           // shifted local prefix
            acc += res;
        }

        idc = idn;
    }

    if (valid && segmode)
        segsum[(size_t)bs * cV + vc] = acc;
}

// out[b,t,v] += sum_{sp<seg} segsum[b,sp,v]; lookback fused; segsum is 4MB
// -> L2/L3-resident for the re-reads.
__global__ __launch_bounds__(256) void wavelm_addbase(
    float* __restrict__ out, const float* __restrict__ segsum)
{
    const int btq = blockIdx.y;          // b*(cT/8) + t-octet
    const int b  = btq >> 6;             // cT/8 = 64
    const int t0 = (btq & 63) * 8;
    const int seg = t0 / GT;
    if (seg == 0) return;                // base is zero: out already final
    const int v4 = blockIdx.x * 256 + threadIdx.x;
    if (v4 >= cV / 4) return;

    const float* sp = segsum + (size_t)b * NSEG * cV + (size_t)v4 * 4;
    v4f base;  base.x = 0.f;  base.y = 0.f;  base.z = 0.f;  base.w = 0.f;
    for (int s = 0; s < seg; ++s) {
        const v4f x = *(const v4f*)(sp + (size_t)s * cV);
        base.x += x.x;  base.y += x.y;  base.z += x.z;  base.w += x.w;
    }

    float* p = out + ((size_t)b * cT + t0) * cV + (size_t)v4 * 4;
#pragma unroll
    for (int k = 0; k < 8; ++k) {
        v4f x = *(v4f*)(p + (size_t)k * cV);
        x.x += base.x;  x.y += base.y;  x.z += base.z;  x.w += base.w;
        *(v4f*)(p + (size_t)k * cV) = x;
    }
}

// fallback full-chain scan (ws too small for segsum)
__global__ __launch_bounds__(256) void wavelm_scan(float* __restrict__ out)
{
    const int g = blockIdx.x * blockDim.x + threadIdx.x;
    if (g >= cB * cV) return;
    const int b = g / cV;
    const int v = g - b * cV;
    float* p = out + (size_t)b * cT * cV + v;
    float acc = 0.f;
#pragma unroll 8
    for (int t = 0; t < cT; ++t) {
        const float c = p[(size_t)t * cV];
        p[(size_t)t * cV] = acc;
        acc += c;
    }
}

extern "C" void kernel_launch(void* const* d_in, const int* in_sizes, int n_in,
                              void* d_out, int out_size, void* d_ws, size_t ws_size,
                              hipStream_t stream)
{
    const int*   ids  = (const int*)d_in[0];
    const float* freq = (const float*)d_in[1];
    const float* amp  = (const float*)d_in[2];
    const float* dec  = (const float*)d_in[3];
    float* out = (float*)d_out;
    float* tab = (float*)d_ws;                           // 28*8000*4 = 896 KB
    float* segsum = tab + (size_t)NPLANE * cV;           // 4*32*8000*4 = 4 MB

    const size_t tab_b = (size_t)NPLANE * cV * sizeof(float);
    const size_t seg_b = (size_t)cB * NSEG * cV * sizeof(float);
    const int segmode = (tab_b + seg_b <= ws_size) ? 1 : 0;

    wavelm_tab<<<(cV + 255) / 256, 256, 0, stream>>>(freq, amp, dec, tab);

    dim3 grid((cV + 255) / 256, cB * cT / GT);           // 32 x 128
    wavelm_g<<<grid, dim3(256), 0, stream>>>(ids, tab, dec, out, segsum, segmode);

    if (segmode) {
        dim3 ab((cV / 4 + 255) / 256, cB * (cT / 8));    // 8 x 256
        wavelm_addbase<<<ab, dim3(256), 0, stream>>>(out, segsum);
    } else {
        const int nchains = cB * cV;
        wavelm_scan<<<(nchains + 255) / 256, dim3(256), 0, stream>>>(out);
    }
}

// Round 6
// 207.221 us; speedup vs baseline: 1.2302x; 1.2302x over previous
//
#include <hip/hip_runtime.h>
#include <math.h>

// WaveLM: logits[b,t,v] = sum_{t'<t} g(id[b,t'], v)
// g(u,v) = 2 * sum_{i,j in 1..H} (A_u/i^dec)(A_v/j^dec) * sinc(2*(f_u*i - f_v*j))
// sinc(2d) = sin(2*pi*d)/(2*pi*d), sinc(0)=1
//
// R11: - R10's 1-v/lane scalar layout REVERTED (issue count grew ~30%:
//        per-lane overhead ops lost their 2-element amortization; VALUBusy
//        90% but 175us). Back to R9's packed 2-v/lane core (132us).
//      - mn/mx guard tracking REMOVED (~10% of issued cycles): the guarded
//        cases (d==0, ptot underflow->0, overflow) all produce non-finite
//        accx/accy (rcp(0)=inf, inf*0=NaN; intermediates can't overflow:
//        |d|<=~200 -> |p6|<=~1e16), so a final |acc|<1e30 check covers the
//        identical domain. Fast-path arithmetic bit-identical to R9.
//      - u-side compression kept (4 s_loads/token: f, A, s1, c1; recurrence
//        identical to wavelm_tab's). GT=16 fused segment scan + id-only
//        prefetch + fused-lookback addbase kept.

typedef float v2f __attribute__((ext_vector_type(2)));
typedef float v4f __attribute__((ext_vector_type(4)));

constexpr int cB = 4, cT = 512, cV = 8000, cH = 7;
constexpr int GT = 16;                // tokens per wavelm_g block == seglen
constexpr int NSEG = cT / GT;         // 32 segments
constexpr int NPLANE = 28;            // table planes

__device__ __forceinline__ v2f pk_add(v2f a, v2f b) {
    v2f d; asm("v_pk_add_f32 %0, %1, %2" : "=v"(d) : "v"(a), "v"(b)); return d;
}
__device__ __forceinline__ v2f pk_mul(v2f a, v2f b) {
    v2f d; asm("v_pk_mul_f32 %0, %1, %2" : "=v"(d) : "v"(a), "v"(b)); return d;
}
__device__ __forceinline__ v2f pk_fma(v2f a, v2f b, v2f c) {
    v2f d; asm("v_pk_fma_f32 %0, %1, %2, %3" : "=v"(d) : "v"(a), "v"(b), "v"(c));
    return d;
}

__global__ __launch_bounds__(256) void wavelm_tab(
    const float* __restrict__ freq, const float* __restrict__ amp,
    const float* __restrict__ decay_p, float* __restrict__ tab)
{
    const int v = blockIdx.x * 256 + threadIdx.x;
    if (v >= cV) return;
    const float decay = decay_p[0];
    const float f = freq[v], A = amp[v];
    const float p2 = __builtin_amdgcn_exp2f(-decay);
    const float p3 = __builtin_amdgcn_exp2f(-decay * 1.5849625007f);
    const float p5 = __builtin_amdgcn_exp2f(-decay * 2.3219280949f);
    const float p7 = __builtin_amdgcn_exp2f(-decay * 2.8073549221f);
    const float rp[7] = {1.f, p2, p3, p2*p2, p5, p2*p3, p7};
    const float xr = f - rintf(f);
    const float s1 = __builtin_amdgcn_sinf(xr);
    const float c1 = __builtin_amdgcn_cosf(xr);
    float s = s1, c = c1;
#pragma unroll
    for (int k = 0; k < cH; ++k) {
        if (k) { const float sp = s, cp = c;
                 s = fmaf(sp, c1,  cp * s1);
                 c = fmaf(cp, c1, -(sp * s1)); }
        tab[(size_t)k * cV + v]        = s;
        tab[(size_t)(7 + k) * cV + v]  = c;
        tab[(size_t)(14 + k) * cV + v] = A * rp[k];
        tab[(size_t)(21 + k) * cV + v] = f * (float)(k + 1);
    }
}

__global__ __launch_bounds__(256) void wavelm_g(
    const int* __restrict__ ids, const float* __restrict__ tab,
    const float* __restrict__ decay_p,
    float* __restrict__ out, float* __restrict__ segsum, const int segmode)
{
    const int bs  = blockIdx.y;                     // (b, seg) flattened
    const int bt0 = bs * GT;
    const int vh  = blockIdx.x * 256 + threadIdx.x; // v-pair index
    const bool valid = (vh * 2 < cV);
    const int vc = valid ? vh : 0;

    // ---- v-side setup once, amortized over GT tokens ----
    const v2f* tp = (const v2f*)tab;                // plane k: k*(cV/2)+vc
    v2f nb[cH], sBw[cH], cBw[cH];
#pragma unroll
    for (int j = 0; j < cH; ++j) {
        const v2f s = tp[(size_t)j * (cV/2) + vc];
        const v2f c = tp[(size_t)(7 + j) * (cV/2) + vc];
        const v2f w = tp[(size_t)(14 + j) * (cV/2) + vc];
        const v2f a = tp[(size_t)(21 + j) * (cV/2) + vc];
        const v2f ws = w * 0.15915494309189535f;    // w/(2pi)
        sBw[j] = s * ws;
        cBw[j] = c * ws;
        nb[j].x = -a.x;  nb[j].y = -a.y;            // negated: d = aU + nb
    }

    // rp[k] = (k+1)^-decay, uniform across lanes; identical ops to wavelm_tab
    const float decay = decay_p[0];
    const float q2 = __builtin_amdgcn_exp2f(-decay);
    const float q3 = __builtin_amdgcn_exp2f(-decay * 1.5849625007f);
    const float q5 = __builtin_amdgcn_exp2f(-decay * 2.3219280949f);
    const float q7 = __builtin_amdgcn_exp2f(-decay * 2.8073549221f);
    const float rp[7] = {1.f, q2, q3, q2*q2, q5, q2*q3, q7};

    v2f acc;  acc.x = 0.f;  acc.y = 0.f;            // running segment prefix

    int idc = ids[bt0];                             // current token id (SGPR)
    for (int g = 0; g < GT; ++g) {
        // prefetch only the NEXT id (1 SGPR); breaks the id->tab serial chain
        const int idn = (g + 1 < GT) ? ids[bt0 + g + 1] : idc;

        // u-side: 4 wave-uniform scalar loads; rest derived in-register
        const float fu  = tab[(size_t)21 * cV + idc];   // f*1 == f
        const float Au  = tab[(size_t)14 * cV + idc];   // A*rp[0] == A
        const float s1u = tab[idc];                     // sin(2pi f)
        const float c1u = tab[(size_t)7 * cV + idc];    // cos(2pi f)

        float accx = 0.f, accy = 0.f;
        float su = s1u, cu = c1u;                   // sin/cos(2pi f (i+1))
#pragma unroll
        for (int i = 0; i < cH; ++i) {
            if (i) { const float sp = su, cp = cu;
                     su = fmaf(sp, c1u,  cp * s1u);
                     cu = fmaf(cp, c1u, -(sp * s1u)); }
            const float au = fu * (float)(i + 1);   // same op as tab plane 21
            v2f ai;  ai.x = au;  ai.y = au;
            v2f d[cH], p[cH];
#pragma unroll
            for (int j = 0; j < cH; ++j) d[j] = pk_add(ai, nb[j]);
            p[0] = d[0];
#pragma unroll
            for (int j = 1; j < cH; ++j) p[j] = pk_mul(p[j-1], d[j]);
            const float ptot = p[6].x * p[6].y;
            const float rt = __builtin_amdgcn_rcpf(ptot);
            v2f r;  r.x = rt * p[6].y;  r.y = rt * p[6].x;   // 1/p6 per comp
            v2f accS = (v2f)0.f, accC = (v2f)0.f;
#pragma unroll
            for (int j = cH - 1; j >= 1; --j) {
                const v2f inv = pk_mul(r, p[j-1]);
                accS = pk_fma(cBw[j], inv, accS);
                accC = pk_fma(sBw[j], inv, accC);
                r = pk_mul(r, d[j]);
            }
            accS = pk_fma(cBw[0], r, accS);
            accC = pk_fma(sBw[0], r, accC);
            // sum_j sn_j*inv_j = su*accS - cu*accC  (per component)
            const float tx = fmaf(su, accS.x, -(cu * accC.x));
            const float ty = fmaf(su, accS.y, -(cu * accC.y));
            accx = fmaf(rp[i], tx, accx);
            accy = fmaf(rp[i], ty, accy);
        }

        // rare guarded path. Any d==0 / underflow-to-0 / overflow produces
        // inf or NaN in accx/accy (rcp(0)=inf; inf*0=NaN; finite overflow of
        // intermediates impossible: |p6| <= ~1e16). NaN fails |x|<1e30 too.
        if (!(fabsf(accx) < 1e30f) || !(fabsf(accy) < 1e30f)) {
            accx = 0.f;  accy = 0.f;
            float s2 = s1u, c2 = c1u;
#pragma unroll
            for (int i = 0; i < cH; ++i) {
                if (i) { const float sp = s2, cp = c2;
                         s2 = fmaf(sp, c1u,  cp * s1u);
                         c2 = fmaf(cp, c1u, -(sp * s1u)); }
                const float au = fu * (float)(i + 1);
                float ax = 0.f, ay = 0.f;
#pragma unroll
                for (int j = 0; j < cH; ++j) {
                    const v2f w = tp[(size_t)(14 + j) * (cV/2) + vc];
                    const float dx = au + nb[j].x;
                    const float dy = au + nb[j].y;
                    const float snx = fmaf(s2, cBw[j].x, -(c2 * sBw[j].x));
                    const float sny = fmaf(s2, cBw[j].y, -(c2 * sBw[j].y));
                    float qx = snx * __builtin_amdgcn_rcpf(dx);
                    float qy = sny * __builtin_amdgcn_rcpf(dy);
                    qx = (dx == 0.f) ? w.x : qx;
                    qy = (dy == 0.f) ? w.y : qy;
                    ax += qx;  ay += qy;
                }
                accx = fmaf(rp[i], ax, accx);
                accy = fmaf(rp[i], ay, accy);
            }
        }

        if (valid) {
            const float A2 = 2.f * Au;
            v2f res;  res.x = A2 * accx;  res.y = A2 * accy;
            const size_t o = (size_t)(bt0 + g) * cV + (size_t)vh * 2;
            // segmode: write shifted local prefix; else raw value
            v2f wv;  wv.x = segmode ? acc.x : res.x;
                     wv.y = segmode ? acc.y : res.y;
            *(v2f*)(out + o) = wv;
            acc = pk_add(acc, res);
        }

        idc = idn;
    }

    if (valid && segmode)
        *(v2f*)(segsum + (size_t)bs * cV + (size_t)vh * 2) = acc;
}

// out[b,t,v] += sum_{sp<seg} segsum[b,sp,v]; lookback fused; segsum is 4MB
// -> L2/L3-resident for the re-reads.
__global__ __launch_bounds__(256) void wavelm_addbase(
    float* __restrict__ out, const float* __restrict__ segsum)
{
    const int btq = blockIdx.y;          // b*(cT/8) + t-octet
    const int b  = btq >> 6;             // cT/8 = 64
    const int t0 = (btq & 63) * 8;
    const int seg = t0 / GT;
    if (seg == 0) return;                // base is zero: out already final
    const int v4 = blockIdx.x * 256 + threadIdx.x;
    if (v4 >= cV / 4) return;

    const float* sp = segsum + (size_t)b * NSEG * cV + (size_t)v4 * 4;
    v4f base;  base.x = 0.f;  base.y = 0.f;  base.z = 0.f;  base.w = 0.f;
    for (int s = 0; s < seg; ++s) {
        const v4f x = *(const v4f*)(sp + (size_t)s * cV);
        base.x += x.x;  base.y += x.y;  base.z += x.z;  base.w += x.w;
    }

    float* p = out + ((size_t)b * cT + t0) * cV + (size_t)v4 * 4;
#pragma unroll
    for (int k = 0; k < 8; ++k) {
        v4f x = *(v4f*)(p + (size_t)k * cV);
        x.x += base.x;  x.y += base.y;  x.z += base.z;  x.w += base.w;
        *(v4f*)(p + (size_t)k * cV) = x;
    }
}

// fallback full-chain scan (ws too small for segsum)
__global__ __launch_bounds__(256) void wavelm_scan(float* __restrict__ out)
{
    const int g = blockIdx.x * blockDim.x + threadIdx.x;
    if (g >= cB * cV) return;
    const int b = g / cV;
    const int v = g - b * cV;
    float* p = out + (size_t)b * cT * cV + v;
    float acc = 0.f;
#pragma unroll 8
    for (int t = 0; t < cT; ++t) {
        const float c = p[(size_t)t * cV];
        p[(size_t)t * cV] = acc;
        acc += c;
    }
}

extern "C" void kernel_launch(void* const* d_in, const int* in_sizes, int n_in,
                              void* d_out, int out_size, void* d_ws, size_t ws_size,
                              hipStream_t stream)
{
    const int*   ids  = (const int*)d_in[0];
    const float* freq = (const float*)d_in[1];
    const float* amp  = (const float*)d_in[2];
    const float* dec  = (const float*)d_in[3];
    float* out = (float*)d_out;
    float* tab = (float*)d_ws;                           // 28*8000*4 = 896 KB
    float* segsum = tab + (size_t)NPLANE * cV;           // 4*32*8000*4 = 4 MB

    const size_t tab_b = (size_t)NPLANE * cV * sizeof(float);
    const size_t seg_b = (size_t)cB * NSEG * cV * sizeof(float);
    const int segmode = (tab_b + seg_b <= ws_size) ? 1 : 0;

    wavelm_tab<<<(cV + 255) / 256, 256, 0, stream>>>(freq, amp, dec, tab);

    dim3 grid((cV / 2 + 255) / 256, cB * cT / GT);       // 16 x 128
    wavelm_g<<<grid, dim3(256), 0, stream>>>(ids, tab, dec, out, segsum, segmode);

    if (segmode) {
        dim3 ab((cV / 4 + 255) / 256, cB * (cT / 8));    // 8 x 256
        wavelm_addbase<<<ab, dim3(256), 0, stream>>>(out, segsum);
    } else {
        const int nchains = cB * cV;
        wavelm_scan<<<(nchains + 255) / 256, dim3(256), 0, stream>>>(out);
    }
}

// Round 7
// 203.419 us; speedup vs baseline: 1.2532x; 1.0187x over previous
//
#include <hip/hip_runtime.h>
#include <math.h>

// WaveLM: logits[b,t,v] = sum_{t'<t} g(id[b,t'], v)
// g(u,v) = 2 * sum_{i,j in 1..H} (A_u/i^dec)(A_v/j^dec) * sinc(2*(f_u*i - f_v*j))
// sinc(2d) = sin(2*pi*d)/(2*pi*d), sinc(0)=1
//
// R12: - wavelm_tab ELIMINATED (one fewer kernel+launch; ~50us of the 207
//        total is launch/graph overhead, so launches are a real lever).
//        v-side planes recomputed in-block from freq[v]/amp[v] with the
//        SAME instruction sequence tab used (v_sin/v_cos of fractional
//        revolutions + angle-addition recurrence; rp from decay) -> values
//        bit-identical to R11. u-side per token: only freq[idc]/amp[idc]
//        (2 uniform s_loads, was 4 dependent tab loads) + sin/cos in VALU;
//        readfirstlane pins s1u/c1u to SGPRs to keep R11's register shape.
//      - Packed 2-v/lane core, finite-check guard, GT=16 fused segment
//        scan, id-only prefetch, fused-lookback addbase all kept from R11.
//      - Wave-uniform early exit for fully-invalid waves restored.

typedef float v2f __attribute__((ext_vector_type(2)));
typedef float v4f __attribute__((ext_vector_type(4)));

constexpr int cB = 4, cT = 512, cV = 8000, cH = 7;
constexpr int GT = 16;                // tokens per wavelm_g block == seglen
constexpr int NSEG = cT / GT;         // 32 segments

__device__ __forceinline__ v2f pk_add(v2f a, v2f b) {
    v2f d; asm("v_pk_add_f32 %0, %1, %2" : "=v"(d) : "v"(a), "v"(b)); return d;
}
__device__ __forceinline__ v2f pk_mul(v2f a, v2f b) {
    v2f d; asm("v_pk_mul_f32 %0, %1, %2" : "=v"(d) : "v"(a), "v"(b)); return d;
}
__device__ __forceinline__ v2f pk_fma(v2f a, v2f b, v2f c) {
    v2f d; asm("v_pk_fma_f32 %0, %1, %2, %3" : "=v"(d) : "v"(a), "v"(b), "v"(c));
    return d;
}
__device__ __forceinline__ float rfl(float x) {
    return __builtin_bit_cast(float,
        __builtin_amdgcn_readfirstlane(__builtin_bit_cast(int, x)));
}

__global__ __launch_bounds__(256) void wavelm_g(
    const int* __restrict__ ids, const float* __restrict__ freq,
    const float* __restrict__ amp, const float* __restrict__ decay_p,
    float* __restrict__ out, float* __restrict__ segsum, const int segmode)
{
    const int bs  = blockIdx.y;                     // (b, seg) flattened
    const int bt0 = bs * GT;
    // wave-uniform early exit for fully-invalid waves
    if ((blockIdx.x * 256 + (int)(threadIdx.x & 192u)) * 2 >= cV) return;
    const int vh  = blockIdx.x * 256 + threadIdx.x; // v-pair index
    const bool valid = (vh * 2 < cV);
    const int vc = valid ? vh : 0;

    // rp[k] = (k+1)^-decay, uniform; identical ops to the old wavelm_tab
    const float decay = decay_p[0];
    const float q2 = __builtin_amdgcn_exp2f(-decay);
    const float q3 = __builtin_amdgcn_exp2f(-decay * 1.5849625007f);
    const float q5 = __builtin_amdgcn_exp2f(-decay * 2.3219280949f);
    const float q7 = __builtin_amdgcn_exp2f(-decay * 2.8073549221f);
    const float rp[7] = {1.f, q2, q3, q2*q2, q5, q2*q3, q7};

    // ---- v-side setup once (tab's math, in-register), amortized over GT ----
    const v2f fv = *(const v2f*)(freq + (size_t)vc * 2);
    const v2f Av = *(const v2f*)(amp  + (size_t)vc * 2);
    v2f nb[cH], sBw[cH], cBw[cH];
    {
        const float xrx = fv.x - rintf(fv.x);
        const float xry = fv.y - rintf(fv.y);
        const float s1x = __builtin_amdgcn_sinf(xrx);
        const float c1x = __builtin_amdgcn_cosf(xrx);
        const float s1y = __builtin_amdgcn_sinf(xry);
        const float c1y = __builtin_amdgcn_cosf(xry);
        float sx = s1x, cx = c1x, sy = s1y, cy = c1y;
#pragma unroll
        for (int k = 0; k < cH; ++k) {
            if (k) {
                const float spx = sx, cpx = cx, spy = sy, cpy = cy;
                sx = fmaf(spx, c1x,  cpx * s1x);
                cx = fmaf(cpx, c1x, -(spx * s1x));
                sy = fmaf(spy, c1y,  cpy * s1y);
                cy = fmaf(cpy, c1y, -(spy * s1y));
            }
            const float wx = Av.x * rp[k];          // tab plane 14+k
            const float wy = Av.y * rp[k];
            const float wsx = wx * 0.15915494309189535f;  // w/(2pi)
            const float wsy = wy * 0.15915494309189535f;
            sBw[k].x = sx * wsx;  sBw[k].y = sy * wsy;
            cBw[k].x = cx * wsx;  cBw[k].y = cy * wsy;
            nb[k].x = -(fv.x * (float)(k + 1));     // tab plane 21+k, negated
            nb[k].y = -(fv.y * (float)(k + 1));
        }
    }

    v2f acc;  acc.x = 0.f;  acc.y = 0.f;            // running segment prefix

    int idc = ids[bt0];                             // current token id (SGPR)
    for (int g = 0; g < GT; ++g) {
        // prefetch only the NEXT id (1 SGPR); breaks the id->load serial chain
        const int idn = (g + 1 < GT) ? ids[bt0 + g + 1] : idc;

        // u-side: 2 wave-uniform scalar loads; sin/cos computed (tab's ops)
        const float fu = freq[idc];
        const float Au = amp[idc];
        const float xru = fu - rintf(fu);
        const float s1u = rfl(__builtin_amdgcn_sinf(xru));
        const float c1u = rfl(__builtin_amdgcn_cosf(xru));

        float accx = 0.f, accy = 0.f;
        float su = s1u, cu = c1u;                   // sin/cos(2pi f (i+1))
#pragma unroll
        for (int i = 0; i < cH; ++i) {
            if (i) { const float sp = su, cp = cu;
                     su = fmaf(sp, c1u,  cp * s1u);
                     cu = fmaf(cp, c1u, -(sp * s1u)); }
            const float au = fu * (float)(i + 1);   // same op as tab plane 21
            v2f ai;  ai.x = au;  ai.y = au;
            v2f d[cH], p[cH];
#pragma unroll
            for (int j = 0; j < cH; ++j) d[j] = pk_add(ai, nb[j]);
            p[0] = d[0];
#pragma unroll
            for (int j = 1; j < cH; ++j) p[j] = pk_mul(p[j-1], d[j]);
            const float ptot = p[6].x * p[6].y;
            const float rt = __builtin_amdgcn_rcpf(ptot);
            v2f r;  r.x = rt * p[6].y;  r.y = rt * p[6].x;   // 1/p6 per comp
            v2f accS = (v2f)0.f, accC = (v2f)0.f;
#pragma unroll
            for (int j = cH - 1; j >= 1; --j) {
                const v2f inv = pk_mul(r, p[j-1]);
                accS = pk_fma(cBw[j], inv, accS);
                accC = pk_fma(sBw[j], inv, accC);
                r = pk_mul(r, d[j]);
            }
            accS = pk_fma(cBw[0], r, accS);
            accC = pk_fma(sBw[0], r, accC);
            // sum_j sn_j*inv_j = su*accS - cu*accC  (per component)
            const float tx = fmaf(su, accS.x, -(cu * accC.x));
            const float ty = fmaf(su, accS.y, -(cu * accC.y));
            accx = fmaf(rp[i], tx, accx);
            accy = fmaf(rp[i], ty, accy);
        }

        // rare guarded path. Any d==0 / underflow-to-0 / overflow produces
        // inf or NaN in accx/accy (rcp(0)=inf; inf*0=NaN; finite overflow of
        // intermediates impossible: |p6| <= ~1e16). NaN fails |x|<1e30 too.
        if (!(fabsf(accx) < 1e30f) || !(fabsf(accy) < 1e30f)) {
            accx = 0.f;  accy = 0.f;
            float s2 = s1u, c2 = c1u;
#pragma unroll
            for (int i = 0; i < cH; ++i) {
                if (i) { const float sp = s2, cp = c2;
                         s2 = fmaf(sp, c1u,  cp * s1u);
                         c2 = fmaf(cp, c1u, -(sp * s1u)); }
                const float au = fu * (float)(i + 1);
                float ax = 0.f, ay = 0.f;
#pragma unroll
                for (int j = 0; j < cH; ++j) {
                    const float wxx = Av.x * rp[j];     // tab plane 14+j
                    const float wyy = Av.y * rp[j];
                    const float dx = au + nb[j].x;
                    const float dy = au + nb[j].y;
                    const float snx = fmaf(s2, cBw[j].x, -(c2 * sBw[j].x));
                    const float sny = fmaf(s2, cBw[j].y, -(c2 * sBw[j].y));
                    float qx = snx * __builtin_amdgcn_rcpf(dx);
                    float qy = sny * __builtin_amdgcn_rcpf(dy);
                    qx = (dx == 0.f) ? wxx : qx;
                    qy = (dy == 0.f) ? wyy : qy;
                    ax += qx;  ay += qy;
                }
                accx = fmaf(rp[i], ax, accx);
                accy = fmaf(rp[i], ay, accy);
            }
        }

        if (valid) {
            const float A2 = 2.f * Au;
            v2f res;  res.x = A2 * accx;  res.y = A2 * accy;
            const size_t o = (size_t)(bt0 + g) * cV + (size_t)vh * 2;
            // segmode: write shifted local prefix; else raw value
            v2f wv;  wv.x = segmode ? acc.x : res.x;
                     wv.y = segmode ? acc.y : res.y;
            *(v2f*)(out + o) = wv;
            acc = pk_add(acc, res);
        }

        idc = idn;
    }

    if (valid && segmode)
        *(v2f*)(segsum + (size_t)bs * cV + (size_t)vh * 2) = acc;
}

// out[b,t,v] += sum_{sp<seg} segsum[b,sp,v]; lookback fused; segsum is 4MB
// -> L2/L3-resident for the re-reads; out re-read mostly L3-hits (just
// written by wavelm_g).
__global__ __launch_bounds__(256) void wavelm_addbase(
    float* __restrict__ out, const float* __restrict__ segsum)
{
    const int btq = blockIdx.y;          // b*(cT/8) + t-octet
    const int b  = btq >> 6;             // cT/8 = 64
    const int t0 = (btq & 63) * 8;
    const int seg = t0 / GT;
    if (seg == 0) return;                // base is zero: out already final
    const int v4 = blockIdx.x * 256 + threadIdx.x;
    if (v4 >= cV / 4) return;

    const float* sp = segsum + (size_t)b * NSEG * cV + (size_t)v4 * 4;
    v4f base;  base.x = 0.f;  base.y = 0.f;  base.z = 0.f;  base.w = 0.f;
    for (int s = 0; s < seg; ++s) {
        const v4f x = *(const v4f*)(sp + (size_t)s * cV);
        base.x += x.x;  base.y += x.y;  base.z += x.z;  base.w += x.w;
    }

    float* p = out + ((size_t)b * cT + t0) * cV + (size_t)v4 * 4;
#pragma unroll
    for (int k = 0; k < 8; ++k) {
        v4f x = *(v4f*)(p + (size_t)k * cV);
        x.x += base.x;  x.y += base.y;  x.z += base.z;  x.w += base.w;
        *(v4f*)(p + (size_t)k * cV) = x;
    }
}

// fallback full-chain scan (ws too small for segsum)
__global__ __launch_bounds__(256) void wavelm_scan(float* __restrict__ out)
{
    const int g = blockIdx.x * blockDim.x + threadIdx.x;
    if (g >= cB * cV) return;
    const int b = g / cV;
    const int v = g - b * cV;
    float* p = out + (size_t)b * cT * cV + v;
    float acc = 0.f;
#pragma unroll 8
    for (int t = 0; t < cT; ++t) {
        const float c = p[(size_t)t * cV];
        p[(size_t)t * cV] = acc;
        acc += c;
    }
}

extern "C" void kernel_launch(void* const* d_in, const int* in_sizes, int n_in,
                              void* d_out, int out_size, void* d_ws, size_t ws_size,
                              hipStream_t stream)
{
    const int*   ids  = (const int*)d_in[0];
    const float* freq = (const float*)d_in[1];
    const float* amp  = (const float*)d_in[2];
    const float* dec  = (const float*)d_in[3];
    float* out = (float*)d_out;
    float* segsum = (float*)d_ws;                        // 4*32*8000*4 = 4 MB

    const size_t seg_b = (size_t)cB * NSEG * cV * sizeof(float);
    const int segmode = (seg_b <= ws_size) ? 1 : 0;

    dim3 grid((cV / 2 + 255) / 256, cB * cT / GT);       // 16 x 128
    wavelm_g<<<grid, dim3(256), 0, stream>>>(ids, freq, amp, dec,
                                             out, segsum, segmode);

    if (segmode) {
        dim3 ab((cV / 4 + 255) / 256, cB * (cT / 8));    // 8 x 256
        wavelm_addbase<<<ab, dim3(256), 0, stream>>>(out, segsum);
    } else {
        const int nchains = cB * cV;
        wavelm_scan<<<(nchains + 255) / 256, dim3(256), 0, stream>>>(out);
    }
}